// Round 1
// baseline (301.570 us; speedup 1.0000x reference)
//
#include <hip/hip_runtime.h>

#define N 8192
#define F 128
#define MARGIN 0.2f
#define NEG_FILL 1e30f

#define BM 64
#define BN 64
#define BK 32
#define NCHUNK 8
#define COLS_PER_CHUNK (N / NCHUNK)
#define LDA_PAD 68  // 64 + 4: breaks bank alignment, keeps 16B alignment for float4 reads

// ---------------------------------------------------------------------------
// ws layout (bytes):
//   [0,        4N)  : na   (float)  row squared norms
//   [4N,       8N)  : pos  (uint)   running hard-positive (float bits, >=0)
//   [8N,      12N)  : neg  (uint)   running hard-negative (float bits, >=0)
//   [12N, 12N+128)  : partial sums (float[32])
// ---------------------------------------------------------------------------

__global__ __launch_bounds__(256) void setup_kernel(const float* __restrict__ A,
                                                    float* __restrict__ na,
                                                    unsigned* __restrict__ pos,
                                                    unsigned* __restrict__ neg) {
    int r = blockIdx.x * 256 + threadIdx.x;
    if (r >= N) return;
    const float4* row = reinterpret_cast<const float4*>(A + r * F);
    float s = 0.0f;
#pragma unroll
    for (int k = 0; k < F / 4; ++k) {
        float4 v = row[k];
        s = fmaf(v.x, v.x, s);
        s = fmaf(v.y, v.y, s);
        s = fmaf(v.z, v.z, s);
        s = fmaf(v.w, v.w, s);
    }
    na[r] = s;
    pos[r] = 0u;                          // distances are >= 0, so 0 is identity for max
    neg[r] = __float_as_uint(NEG_FILL);   // identity for min
}

__global__ __launch_bounds__(256) void hard_mine(const float* __restrict__ A,
                                                 const int* __restrict__ ids,
                                                 const float* __restrict__ na,
                                                 unsigned* __restrict__ pos,
                                                 unsigned* __restrict__ neg) {
    // K-major tiles so the inner loop does contiguous float4 LDS reads.
    __shared__ float As[F][LDA_PAD];  // 128 x 68 x 4B = 34816 B (A-tile resident all block)
    __shared__ float Bs[BK][BN];      // 32 x 64 x 4B  =  8192 B (B chunked over K)

    const int tid = threadIdx.x;
    const int tx = tid & 15;   // 16 col-groups
    const int ty = tid >> 4;   // 16 row-groups
    const int rowsbase = blockIdx.x * BM;
    const int colchunk = blockIdx.y * COLS_PER_CHUNK;

    // One-time A-tile load: 64 rows x 128 k -> k-major LDS. Coalesced 128B rows.
#pragma unroll
    for (int s = 0; s < 8; ++s) {
        int q = tid + s * 256;   // 0..2047
        int row = q >> 5;        // 0..63
        int c4 = q & 31;         // k = 4*c4
        float4 v = *reinterpret_cast<const float4*>(A + (rowsbase + row) * F + c4 * 4);
        As[c4 * 4 + 0][row] = v.x;
        As[c4 * 4 + 1][row] = v.y;
        As[c4 * 4 + 2][row] = v.z;
        As[c4 * 4 + 3][row] = v.w;
    }

    float myna[4];
    int myid[4];
#pragma unroll
    for (int u = 0; u < 4; ++u) {
        int r = rowsbase + ty * 4 + u;
        myna[u] = na[r];
        myid[u] = ids[r];
    }

    float pmax[4] = {0.0f, 0.0f, 0.0f, 0.0f};
    float nmin[4] = {NEG_FILL, NEG_FILL, NEG_FILL, NEG_FILL};

    for (int cb = 0; cb < COLS_PER_CHUNK; cb += BN) {
        const int colbase = colchunk + cb;
        float acc[4][4] = {};

#pragma unroll
        for (int kk = 0; kk < F; kk += BK) {
            __syncthreads();  // Bs (and first time As) writes vs reads
            // Stage B chunk: 64 cols x 32 k, coalesced 128B per col-row.
#pragma unroll
            for (int s = 0; s < 2; ++s) {
                int q = tid + s * 256;  // 0..511
                int col = q >> 3;       // 0..63
                int c4 = q & 7;         // k = kk + 4*c4
                float4 v = *reinterpret_cast<const float4*>(A + (colbase + col) * F + kk + c4 * 4);
                Bs[c4 * 4 + 0][col] = v.x;
                Bs[c4 * 4 + 1][col] = v.y;
                Bs[c4 * 4 + 2][col] = v.z;
                Bs[c4 * 4 + 3][col] = v.w;
            }
            __syncthreads();

#pragma unroll
            for (int k = 0; k < BK; ++k) {
                float4 av = *reinterpret_cast<const float4*>(&As[kk + k][ty * 4]);
                float4 bv = *reinterpret_cast<const float4*>(&Bs[k][tx * 4]);
                float a[4] = {av.x, av.y, av.z, av.w};
                float b[4] = {bv.x, bv.y, bv.z, bv.w};
#pragma unroll
                for (int u = 0; u < 4; ++u)
#pragma unroll
                    for (int v = 0; v < 4; ++v)
                        acc[u][v] = fmaf(a[u], b[v], acc[u][v]);
            }
        }

        // Epilogue: distances + hard mining for this 64x64 tile.
#pragma unroll
        for (int v = 0; v < 4; ++v) {
            int j = colbase + tx * 4 + v;
            int jid = ids[j];
            float nb = na[j];
#pragma unroll
            for (int u = 0; u < 4; ++u) {
                float d2 = myna[u] + nb - 2.0f * acc[u][v];
                float d = sqrtf(fmaxf(d2, 0.0f) + 1e-12f);
                if (jid == myid[u]) pmax[u] = fmaxf(pmax[u], d);
                else                nmin[u] = fminf(nmin[u], d);
            }
        }
    }

    // Reduce across the 16 tx lanes (each group shares the same 4 rows).
#pragma unroll
    for (int m = 1; m < 16; m <<= 1) {
#pragma unroll
        for (int u = 0; u < 4; ++u) {
            pmax[u] = fmaxf(pmax[u], __shfl_xor(pmax[u], m, 64));
            nmin[u] = fminf(nmin[u], __shfl_xor(nmin[u], m, 64));
        }
    }
    if (tx == 0) {
#pragma unroll
        for (int u = 0; u < 4; ++u) {
            int r = rowsbase + ty * 4 + u;
            atomicMax(&pos[r], __float_as_uint(pmax[u]));  // uint order == float order (>=0)
            atomicMin(&neg[r], __float_as_uint(nmin[u]));
        }
    }
}

__global__ __launch_bounds__(256) void row_loss_kernel(const unsigned* __restrict__ pos,
                                                       const unsigned* __restrict__ neg,
                                                       float* __restrict__ partial) {
    int r = blockIdx.x * 256 + threadIdx.x;
    float hp = __uint_as_float(pos[r]);
    float hn = __uint_as_float(neg[r]);  // 1e30 if no negatives -> loss clamps to 0
    float loss = fmaxf(MARGIN + hp - hn, 0.0f);
#pragma unroll
    for (int m = 32; m >= 1; m >>= 1) loss += __shfl_xor(loss, m, 64);
    __shared__ float wsum[4];
    int lane = threadIdx.x & 63;
    int wave = threadIdx.x >> 6;
    if (lane == 0) wsum[wave] = loss;
    __syncthreads();
    if (threadIdx.x == 0) partial[blockIdx.x] = wsum[0] + wsum[1] + wsum[2] + wsum[3];
}

__global__ __launch_bounds__(64) void final_kernel(const float* __restrict__ partial,
                                                   float* __restrict__ out) {
    float v = (threadIdx.x < 32) ? partial[threadIdx.x] : 0.0f;
#pragma unroll
    for (int m = 32; m >= 1; m >>= 1) v += __shfl_xor(v, m, 64);
    if (threadIdx.x == 0) out[0] = v * (1.0f / (float)N);  // LOSS_FACTOR == 1
}

extern "C" void kernel_launch(void* const* d_in, const int* in_sizes, int n_in,
                              void* d_out, int out_size, void* d_ws, size_t ws_size,
                              hipStream_t stream) {
    const float* A = (const float*)d_in[0];
    const int* ids = (const int*)d_in[1];
    float* out = (float*)d_out;

    char* ws = (char*)d_ws;
    float* na = (float*)ws;
    unsigned* pos = (unsigned*)(ws + 4 * N);
    unsigned* neg = (unsigned*)(ws + 8 * N);
    float* partial = (float*)(ws + 12 * N);

    setup_kernel<<<N / 256, 256, 0, stream>>>(A, na, pos, neg);
    dim3 grid(N / BM, NCHUNK);
    hard_mine<<<grid, 256, 0, stream>>>(A, ids, na, pos, neg);
    row_loss_kernel<<<N / 256, 256, 0, stream>>>(pos, neg, partial);
    final_kernel<<<1, 64, 0, stream>>>(partial, out);
}

// Round 2
// 83.519 us; speedup vs baseline: 3.6108x; 3.6108x over previous
//
#include <hip/hip_runtime.h>

#define N 8192
#define F 128
#define MARGIN 0.2f
#define NEG_FILL 1e30f
#define NEG_FILL_BITS 0x7149f2cau  // bits of 1e30f

typedef unsigned short ushort_t;
typedef unsigned int uint_t;
typedef short bf16x8 __attribute__((ext_vector_type(8)));
typedef float f32x4 __attribute__((ext_vector_type(4)));

// ---------------------------------------------------------------------------
// ws layout (bytes):
//   [0,        4N)      : na   (float)  exact fp32 row squared norms
//   [4N,       8N)      : pos  (uint)   running hard-positive d (float bits)
//   [8N,      12N)      : neg  (uint)   running hard-negative d (float bits)
//   [12N,  12N+4096)    : partial sums (float[32]) + pad
//   [12N+4096, +4MB)    : H    (bf16)   [N][256] = [hi(128) | lo(128)]
// ---------------------------------------------------------------------------

__device__ __forceinline__ ushort_t f2bf(float x) {
    uint_t u = __float_as_uint(x);
    uint_t r = (u + 0x7FFFu + ((u >> 16) & 1u)) >> 16;  // round-to-nearest-even
    return (ushort_t)r;
}
__device__ __forceinline__ float bf2f(ushort_t b) {
    return __uint_as_float(((uint_t)b) << 16);
}

__global__ __launch_bounds__(256) void convert_kernel(const float* __restrict__ A,
                                                      ushort_t* __restrict__ H) {
    int t = blockIdx.x * 256 + threadIdx.x;  // 0 .. N*32-1
    int row = t >> 5, kg = t & 31;
    float4 v = *reinterpret_cast<const float4*>(A + row * F + kg * 4);
    float f[4] = {v.x, v.y, v.z, v.w};
    ushort_t hi[4], lo[4];
#pragma unroll
    for (int j = 0; j < 4; ++j) {
        hi[j] = f2bf(f[j]);
        lo[j] = f2bf(f[j] - bf2f(hi[j]));
    }
    *reinterpret_cast<ushort4*>(H + row * 256 + kg * 4) =
        make_ushort4(hi[0], hi[1], hi[2], hi[3]);
    *reinterpret_cast<ushort4*>(H + row * 256 + 128 + kg * 4) =
        make_ushort4(lo[0], lo[1], lo[2], lo[3]);
}

__global__ __launch_bounds__(256) void setup_kernel(const float* __restrict__ A,
                                                    float* __restrict__ na,
                                                    uint_t* __restrict__ pos,
                                                    uint_t* __restrict__ neg) {
    int r = blockIdx.x * 256 + threadIdx.x;
    const float4* row = reinterpret_cast<const float4*>(A + r * F);
    float s = 0.0f;
#pragma unroll
    for (int k = 0; k < F / 4; ++k) {
        float4 v = row[k];
        s = fmaf(v.x, v.x, s);
        s = fmaf(v.y, v.y, s);
        s = fmaf(v.z, v.z, s);
        s = fmaf(v.w, v.w, s);
    }
    na[r] = s;
    pos[r] = 0u;
    neg[r] = NEG_FILL_BITS;
}

// 128x128 output tile per block, 4 waves in 2x2; block loops over 8 col-tiles.
// K = 384 effective: 3 passes (hi*hi, hi*lo, lo*hi) x 128, BK=64 -> 6 K-steps.
__global__ __launch_bounds__(256) void hard_mine_mfma(const ushort_t* __restrict__ H,
                                                      const int* __restrict__ ids,
                                                      const float* __restrict__ na,
                                                      uint_t* __restrict__ pos,
                                                      uint_t* __restrict__ neg) {
    __shared__ __align__(16) ushort_t AsU[128 * 64];  // 16 KB, [row][slot^=(row&7)]
    __shared__ __align__(16) ushort_t BsU[128 * 64];  // 16 KB
    __shared__ uint_t ls_pos[128];
    __shared__ uint_t ls_neg[128];

    const int tid = threadIdx.x;
    const int w = tid >> 6, lane = tid & 63;
    const int wr = w >> 1, wc = w & 1;  // wave's 64x64 quadrant
    const int rowbase = blockIdx.x * 128;
    const int chunkbase = blockIdx.y * 1024;

    // row ids for mining (C-layout rows: (lane>>4)*4 + q)
    int myid[4][4];
#pragma unroll
    for (int m = 0; m < 4; ++m)
#pragma unroll
        for (int q = 0; q < 4; ++q)
            myid[m][q] = ids[rowbase + wr * 64 + m * 16 + (lane >> 4) * 4 + q];

    // mining state in (nb - 2*S) space; na added at the end (monotonic in d2, d)
    float pm[4][4], nm[4][4];
#pragma unroll
    for (int m = 0; m < 4; ++m)
#pragma unroll
        for (int q = 0; q < 4; ++q) {
            pm[m][q] = -NEG_FILL;
            nm[m][q] = NEG_FILL;
        }

    for (int ct = 0; ct < 8; ++ct) {
        const int colbase = chunkbase + ct * 128;

        int jd[4];
        float nb[4];
#pragma unroll
        for (int n = 0; n < 4; ++n) {
            int j = colbase + wc * 64 + n * 16 + (lane & 15);
            jd[n] = ids[j];
            nb[n] = na[j];
        }

        f32x4 acc[4][4];
#pragma unroll
        for (int m = 0; m < 4; ++m)
#pragma unroll
            for (int n = 0; n < 4; ++n)
                acc[m][n] = (f32x4)0.0f;

#pragma unroll
        for (int s = 0; s < 6; ++s) {
            const int p = s >> 1;
            const int koff = (s & 1) * 64;
            const int Acol = ((p == 2) ? 128 : 0) + koff;
            const int Bcol = ((p == 1) ? 128 : 0) + koff;

            __syncthreads();  // previous compute done before overwriting LDS
            // Stage: linear LDS dest (global_load_lds), inverse-swizzled source.
#pragma unroll
            for (int i = 0; i < 4; ++i) {
                int chunk = w * 4 + i;              // 0..15 (1 KB each)
                int row = chunk * 8 + (lane >> 3);  // 0..127
                int ss = (lane & 7) ^ (row & 7);    // source slot (involution)
                const ushort_t* ga = H + (size_t)(rowbase + row) * 256 + Acol + ss * 8;
                const ushort_t* gb = H + (size_t)(colbase + row) * 256 + Bcol + ss * 8;
                __builtin_amdgcn_global_load_lds(
                    (const __attribute__((address_space(1))) uint_t*)ga,
                    (__attribute__((address_space(3))) uint_t*)(AsU + chunk * 512), 16, 0, 0);
                __builtin_amdgcn_global_load_lds(
                    (const __attribute__((address_space(1))) uint_t*)gb,
                    (__attribute__((address_space(3))) uint_t*)(BsU + chunk * 512), 16, 0, 0);
            }
            __syncthreads();  // vmcnt(0) drain at barrier

#pragma unroll
            for (int ks = 0; ks < 2; ++ks) {
                bf16x8 af[4], bfr[4];
                const int sl = ks * 4 + (lane >> 4);  // logical 16B slot
#pragma unroll
                for (int m = 0; m < 4; ++m) {
                    int r = wr * 64 + m * 16 + (lane & 15);
                    int ph = sl ^ (r & 7);
                    af[m] = *reinterpret_cast<const bf16x8*>(AsU + r * 64 + ph * 8);
                }
#pragma unroll
                for (int n = 0; n < 4; ++n) {
                    int c = wc * 64 + n * 16 + (lane & 15);
                    int ph = sl ^ (c & 7);
                    bfr[n] = *reinterpret_cast<const bf16x8*>(BsU + c * 64 + ph * 8);
                }
#pragma unroll
                for (int m = 0; m < 4; ++m)
#pragma unroll
                    for (int n = 0; n < 4; ++n)
                        acc[m][n] = __builtin_amdgcn_mfma_f32_16x16x32_bf16(
                            af[m], bfr[n], acc[m][n], 0, 0, 0);
            }
        }

        // Mining epilogue for this 128-col tile (d2-monotone space, no sqrt).
#pragma unroll
        for (int n = 0; n < 4; ++n) {
            const float nbv = nb[n];
            const int jdv = jd[n];
#pragma unroll
            for (int m = 0; m < 4; ++m)
#pragma unroll
                for (int q = 0; q < 4; ++q) {
                    float val = fmaf(-2.0f, acc[m][n][q], nbv);
                    bool same = (jdv == myid[m][q]);
                    pm[m][q] = same ? fmaxf(pm[m][q], val) : pm[m][q];
                    nm[m][q] = same ? nm[m][q] : fminf(nm[m][q], val);
                }
        }
    }

    // Reduce across the 16 column-lanes (same output row).
#pragma unroll
    for (int mk = 1; mk < 16; mk <<= 1)
#pragma unroll
        for (int m = 0; m < 4; ++m)
#pragma unroll
            for (int q = 0; q < 4; ++q) {
                pm[m][q] = fmaxf(pm[m][q], __shfl_xor(pm[m][q], mk, 64));
                nm[m][q] = fminf(nm[m][q], __shfl_xor(nm[m][q], mk, 64));
            }

    __syncthreads();
    if (tid < 128) {
        ls_pos[tid] = 0u;
        ls_neg[tid] = NEG_FILL_BITS;
    }
    __syncthreads();
    if ((lane & 15) == 0) {
#pragma unroll
        for (int m = 0; m < 4; ++m)
#pragma unroll
            for (int q = 0; q < 4; ++q) {
                int rl = wr * 64 + m * 16 + (lane >> 4) * 4 + q;
                float nav = na[rowbase + rl];
                float hp = sqrtf(fmaxf(nav + pm[m][q], 0.0f) + 1e-12f);
                float hn = sqrtf(fmaxf(nav + nm[m][q], 0.0f) + 1e-12f);
                atomicMax(&ls_pos[rl], __float_as_uint(hp));
                atomicMin(&ls_neg[rl], __float_as_uint(hn));
            }
    }
    __syncthreads();
    if (tid < 128) {
        atomicMax(&pos[rowbase + tid], ls_pos[tid]);
        atomicMin(&neg[rowbase + tid], ls_neg[tid]);
    }
}

__global__ __launch_bounds__(256) void row_loss_kernel(const uint_t* __restrict__ pos,
                                                       const uint_t* __restrict__ neg,
                                                       float* __restrict__ partial) {
    int r = blockIdx.x * 256 + threadIdx.x;
    float hp = __uint_as_float(pos[r]);
    float hn = __uint_as_float(neg[r]);  // huge if no negatives -> clamps to 0
    float loss = fmaxf(MARGIN + hp - hn, 0.0f);
#pragma unroll
    for (int m = 32; m >= 1; m >>= 1) loss += __shfl_xor(loss, m, 64);
    __shared__ float wsum[4];
    int lane = threadIdx.x & 63;
    int wave = threadIdx.x >> 6;
    if (lane == 0) wsum[wave] = loss;
    __syncthreads();
    if (threadIdx.x == 0) partial[blockIdx.x] = wsum[0] + wsum[1] + wsum[2] + wsum[3];
}

__global__ __launch_bounds__(64) void final_kernel(const float* __restrict__ partial,
                                                   float* __restrict__ out) {
    float v = (threadIdx.x < 32) ? partial[threadIdx.x] : 0.0f;
#pragma unroll
    for (int m = 32; m >= 1; m >>= 1) v += __shfl_xor(v, m, 64);
    if (threadIdx.x == 0) out[0] = v * (1.0f / (float)N);  // LOSS_FACTOR == 1
}

extern "C" void kernel_launch(void* const* d_in, const int* in_sizes, int n_in,
                              void* d_out, int out_size, void* d_ws, size_t ws_size,
                              hipStream_t stream) {
    (void)in_sizes; (void)n_in; (void)out_size; (void)ws_size;
    const float* A = (const float*)d_in[0];
    const int* ids = (const int*)d_in[1];
    float* out = (float*)d_out;

    char* ws = (char*)d_ws;
    float* na = (float*)ws;
    uint_t* pos = (uint_t*)(ws + 4 * N);
    uint_t* neg = (uint_t*)(ws + 8 * N);
    float* partial = (float*)(ws + 12 * N);
    ushort_t* H = (ushort_t*)(ws + 12 * N + 4096);

    convert_kernel<<<N * 32 / 256, 256, 0, stream>>>(A, H);
    setup_kernel<<<N / 256, 256, 0, stream>>>(A, na, pos, neg);
    dim3 grid(N / 128, 8);
    hard_mine_mfma<<<grid, 256, 0, stream>>>(H, ids, na, pos, neg);
    row_loss_kernel<<<N / 256, 256, 0, stream>>>(pos, neg, partial);
    final_kernel<<<1, 64, 0, stream>>>(partial, out);
}

// Round 3
// 60.983 us; speedup vs baseline: 4.9452x; 1.3696x over previous
//
#include <hip/hip_runtime.h>

#define N 8192
#define F 128
#define MARGIN 0.2f
#define NEG_FILL 1e30f
#define NEG_FILL_BITS 0x7149f2cau  // bits of 1e30f
#define NINF (-3.0e38f)
#define PINF (3.0e38f)

typedef unsigned short ushort_t;
typedef unsigned int uint_t;
typedef _Float16 half8 __attribute__((ext_vector_type(8)));
typedef float f32x4 __attribute__((ext_vector_type(4)));

// ---------------------------------------------------------------------------
// ws layout (bytes):
//   [0,        4N)      : na   (float)  exact fp32 row squared norms
//   [4N,       8N)      : pos  (uint)   running hard-positive d (float bits)
//   [8N,      12N)      : neg  (uint)   running hard-negative d (float bits)
//   [12N,  12N+4096)    : partial sums (float[32]) + pad
//   [12N+4096, +2MB)    : H    (fp16)   [N][128]
// ---------------------------------------------------------------------------

// Fused: fp32 -> fp16 conversion + exact fp32 row norms + pos/neg init.
__global__ __launch_bounds__(256) void prep_kernel(const float* __restrict__ A,
                                                   ushort_t* __restrict__ H,
                                                   float* __restrict__ na,
                                                   uint_t* __restrict__ pos,
                                                   uint_t* __restrict__ neg) {
    int t = blockIdx.x * 256 + threadIdx.x;  // 0 .. N*32-1
    int row = t >> 5, kg = t & 31;
    float4 v = *reinterpret_cast<const float4*>(A + row * F + kg * 4);
    float f[4] = {v.x, v.y, v.z, v.w};
    ushort4 h;
    {
        _Float16 h0 = (_Float16)f[0], h1 = (_Float16)f[1], h2 = (_Float16)f[2], h3 = (_Float16)f[3];
        __builtin_memcpy(&h.x, &h0, 2);
        __builtin_memcpy(&h.y, &h1, 2);
        __builtin_memcpy(&h.z, &h2, 2);
        __builtin_memcpy(&h.w, &h3, 2);
    }
    *reinterpret_cast<ushort4*>(H + row * F + kg * 4) = h;
    float s = fmaf(f[0], f[0], fmaf(f[1], f[1], fmaf(f[2], f[2], f[3] * f[3])));
#pragma unroll
    for (int m = 1; m <= 16; m <<= 1) s += __shfl_xor(s, m, 64);  // 32-lane groups = one row
    if (kg == 0) {
        na[row] = s;
        pos[row] = 0u;
        neg[row] = NEG_FILL_BITS;
    }
}

// One 128x128 upper-triangular block-tile per block (2080 blocks).
// fp16 MFMA, K=128 in 2 steps of BK=64; dual-side (row+col) hard mining.
__global__ __launch_bounds__(256) void hard_mine_mfma(const ushort_t* __restrict__ H,
                                                      const int* __restrict__ ids,
                                                      const float* __restrict__ na,
                                                      uint_t* __restrict__ pos,
                                                      uint_t* __restrict__ neg) {
    __shared__ __align__(16) ushort_t AsU[128 * 64];  // 16 KB, slot ^= row&7 swizzle
    __shared__ __align__(16) ushort_t BsU[128 * 64];  // 16 KB
    __shared__ uint_t ls_rp[128], ls_rn[128], ls_cp[128], ls_cn[128];

    const int tid = threadIdx.x;
    const int w = tid >> 6, lane = tid & 63;
    const int wr = w >> 1, wc = w & 1;  // wave's 64x64 quadrant

    // triangular decode: tile t -> (bi <= bj)
    int t = blockIdx.x;
    int bj = (int)((sqrtf(8.0f * (float)t + 1.0f) - 1.0f) * 0.5f);
    while ((bj + 1) * (bj + 2) / 2 <= t) ++bj;
    while (bj * (bj + 1) / 2 > t) --bj;
    const int bi = t - bj * (bj + 1) / 2;
    const int rowbase = bi * 128;
    const int colbase = bj * 128;

    // row-side ids / norms (issued early; L2-resident)
    int myid[4][4];
    float myna[4][4];
#pragma unroll
    for (int m = 0; m < 4; ++m)
#pragma unroll
        for (int q = 0; q < 4; ++q) {
            int r = rowbase + wr * 64 + m * 16 + (lane >> 4) * 4 + q;
            myid[m][q] = ids[r];
            myna[m][q] = na[r];
        }
    int jd[4];
    float nb[4];
#pragma unroll
    for (int n = 0; n < 4; ++n) {
        int j = colbase + wc * 64 + n * 16 + (lane & 15);
        jd[n] = ids[j];
        nb[n] = na[j];
    }

    if (tid < 128) {
        ls_rp[tid] = 0u;
        ls_rn[tid] = NEG_FILL_BITS;
        ls_cp[tid] = 0u;
        ls_cn[tid] = NEG_FILL_BITS;
    }

    f32x4 acc[4][4];
#pragma unroll
    for (int m = 0; m < 4; ++m)
#pragma unroll
        for (int n = 0; n < 4; ++n)
            acc[m][n] = (f32x4)0.0f;

#pragma unroll
    for (int s = 0; s < 2; ++s) {
        const int koff = s * 64;
        __syncthreads();  // prev compute done (and ls-init visible) before LDS overwrite
#pragma unroll
        for (int i = 0; i < 4; ++i) {
            int chunk = w * 4 + i;              // 0..15 (1 KB each)
            int row = chunk * 8 + (lane >> 3);  // 0..127
            int ss = (lane & 7) ^ (row & 7);    // inverse-swizzled source slot
            const ushort_t* ga = H + (size_t)(rowbase + row) * F + koff + ss * 8;
            const ushort_t* gb = H + (size_t)(colbase + row) * F + koff + ss * 8;
            __builtin_amdgcn_global_load_lds(
                (const __attribute__((address_space(1))) uint_t*)ga,
                (__attribute__((address_space(3))) uint_t*)(AsU + chunk * 512), 16, 0, 0);
            __builtin_amdgcn_global_load_lds(
                (const __attribute__((address_space(1))) uint_t*)gb,
                (__attribute__((address_space(3))) uint_t*)(BsU + chunk * 512), 16, 0, 0);
        }
        __syncthreads();  // vmcnt(0) drain at barrier

#pragma unroll
        for (int ks = 0; ks < 2; ++ks) {
            half8 af[4], bfr[4];
            const int sl = ks * 4 + (lane >> 4);  // logical 16B slot
#pragma unroll
            for (int m = 0; m < 4; ++m) {
                int r = wr * 64 + m * 16 + (lane & 15);
                int ph = sl ^ (r & 7);
                af[m] = *reinterpret_cast<const half8*>(AsU + r * 64 + ph * 8);
            }
#pragma unroll
            for (int n = 0; n < 4; ++n) {
                int c = wc * 64 + n * 16 + (lane & 15);
                int ph = sl ^ (c & 7);
                bfr[n] = *reinterpret_cast<const half8*>(BsU + c * 64 + ph * 8);
            }
#pragma unroll
            for (int m = 0; m < 4; ++m)
#pragma unroll
                for (int n = 0; n < 4; ++n)
                    acc[m][n] = __builtin_amdgcn_mfma_f32_16x16x32_f16(
                        af[m], bfr[n], acc[m][n], 0, 0, 0);
        }
    }

    // --- dual-side mining epilogue (d2-monotone spaces, no sqrt in loop) ---
    float pm[4][4], nm[4][4];   // row-side: val = nb[j] - 2S  (fixed row)
    float cp[4], cn[4];         // col-side: val = na[i] - 2S  (fixed col)
#pragma unroll
    for (int m = 0; m < 4; ++m)
#pragma unroll
        for (int q = 0; q < 4; ++q) {
            pm[m][q] = NINF;
            nm[m][q] = PINF;
        }
#pragma unroll
    for (int n = 0; n < 4; ++n) {
        cp[n] = NINF;
        cn[n] = PINF;
    }

#pragma unroll
    for (int n = 0; n < 4; ++n) {
        const float nbv = nb[n];
        const int jdv = jd[n];
#pragma unroll
        for (int m = 0; m < 4; ++m)
#pragma unroll
            for (int q = 0; q < 4; ++q) {
                float a = acc[m][n][q];
                float vr = fmaf(-2.0f, a, nbv);
                float vc = fmaf(-2.0f, a, myna[m][q]);
                bool same = (jdv == myid[m][q]);
                pm[m][q] = fmaxf(pm[m][q], same ? vr : NINF);
                nm[m][q] = fminf(nm[m][q], same ? PINF : vr);
                cp[n] = fmaxf(cp[n], same ? vc : NINF);
                cn[n] = fminf(cn[n], same ? PINF : vc);
            }
    }

    // row-side: reduce across the 16 column-lanes (lane&15)
#pragma unroll
    for (int mk = 1; mk < 16; mk <<= 1)
#pragma unroll
        for (int m = 0; m < 4; ++m)
#pragma unroll
            for (int q = 0; q < 4; ++q) {
                pm[m][q] = fmaxf(pm[m][q], __shfl_xor(pm[m][q], mk, 64));
                nm[m][q] = fminf(nm[m][q], __shfl_xor(nm[m][q], mk, 64));
            }
    // col-side: reduce across the 4 row-groups (lane>>4)
#pragma unroll
    for (int mk = 16; mk < 64; mk <<= 1)
#pragma unroll
        for (int n = 0; n < 4; ++n) {
            cp[n] = fmaxf(cp[n], __shfl_xor(cp[n], mk, 64));
            cn[n] = fminf(cn[n], __shfl_xor(cn[n], mk, 64));
        }

    __syncthreads();  // ls arrays initialized & LDS tile reads done
    if ((lane & 15) == 0) {
#pragma unroll
        for (int m = 0; m < 4; ++m)
#pragma unroll
            for (int q = 0; q < 4; ++q) {
                int rl = wr * 64 + m * 16 + (lane >> 4) * 4 + q;
                float hp = sqrtf(fmaxf(myna[m][q] + pm[m][q], 0.0f) + 1e-12f);
                float hn = sqrtf(fmaxf(myna[m][q] + nm[m][q], 0.0f) + 1e-12f);
                atomicMax(&ls_rp[rl], __float_as_uint(hp));
                atomicMin(&ls_rn[rl], __float_as_uint(hn));
            }
    }
    if (lane < 16) {
#pragma unroll
        for (int n = 0; n < 4; ++n) {
            int cl = wc * 64 + n * 16 + lane;
            float hp = sqrtf(fmaxf(nb[n] + cp[n], 0.0f) + 1e-12f);
            float hn = sqrtf(fmaxf(nb[n] + cn[n], 0.0f) + 1e-12f);
            atomicMax(&ls_cp[cl], __float_as_uint(hp));
            atomicMin(&ls_cn[cl], __float_as_uint(hn));
        }
    }
    __syncthreads();
    if (tid < 128) {
        atomicMax(&pos[rowbase + tid], ls_rp[tid]);
        atomicMin(&neg[rowbase + tid], ls_rn[tid]);
        atomicMax(&pos[colbase + tid], ls_cp[tid]);
        atomicMin(&neg[colbase + tid], ls_cn[tid]);
    }
}

__global__ __launch_bounds__(256) void row_loss_kernel(const uint_t* __restrict__ pos,
                                                       const uint_t* __restrict__ neg,
                                                       float* __restrict__ partial) {
    int r = blockIdx.x * 256 + threadIdx.x;
    float hp = __uint_as_float(pos[r]);
    float hn = __uint_as_float(neg[r]);  // huge if no negatives -> clamps to 0
    float loss = fmaxf(MARGIN + hp - hn, 0.0f);
#pragma unroll
    for (int m = 32; m >= 1; m >>= 1) loss += __shfl_xor(loss, m, 64);
    __shared__ float wsum[4];
    int lane = threadIdx.x & 63;
    int wave = threadIdx.x >> 6;
    if (lane == 0) wsum[wave] = loss;
    __syncthreads();
    if (threadIdx.x == 0) partial[blockIdx.x] = wsum[0] + wsum[1] + wsum[2] + wsum[3];
}

__global__ __launch_bounds__(64) void final_kernel(const float* __restrict__ partial,
                                                   float* __restrict__ out) {
    float v = (threadIdx.x < 32) ? partial[threadIdx.x] : 0.0f;
#pragma unroll
    for (int m = 32; m >= 1; m >>= 1) v += __shfl_xor(v, m, 64);
    if (threadIdx.x == 0) out[0] = v * (1.0f / (float)N);  // LOSS_FACTOR == 1
}

extern "C" void kernel_launch(void* const* d_in, const int* in_sizes, int n_in,
                              void* d_out, int out_size, void* d_ws, size_t ws_size,
                              hipStream_t stream) {
    (void)in_sizes; (void)n_in; (void)out_size; (void)ws_size;
    const float* A = (const float*)d_in[0];
    const int* ids = (const int*)d_in[1];
    float* out = (float*)d_out;

    char* ws = (char*)d_ws;
    float* na = (float*)ws;
    uint_t* pos = (uint_t*)(ws + 4 * N);
    uint_t* neg = (uint_t*)(ws + 8 * N);
    float* partial = (float*)(ws + 12 * N);
    ushort_t* H = (ushort_t*)(ws + 12 * N + 4096);

    prep_kernel<<<N * 32 / 256, 256, 0, stream>>>(A, H, na, pos, neg);
    hard_mine_mfma<<<64 * 65 / 2, 256, 0, stream>>>(H, ids, na, pos, neg);
    row_loss_kernel<<<N / 256, 256, 0, stream>>>(pos, neg, partial);
    final_kernel<<<1, 64, 0, stream>>>(partial, out);
}

// Round 4
// 55.289 us; speedup vs baseline: 5.4544x; 1.1030x over previous
//
#include <hip/hip_runtime.h>

#define N 8192
#define F 128
#define MARGIN 0.2f
#define NEG_FILL 1e30f
#define NEG_FILL_BITS 0x7149f2cau  // bits of 1e30f
#define NINF (-3.0e38f)
#define PINF (3.0e38f)
#define NUM_IDS 512

typedef unsigned short ushort_t;
typedef unsigned int uint_t;
typedef _Float16 half8 __attribute__((ext_vector_type(8)));
typedef float f32x4 __attribute__((ext_vector_type(4)));

// ---------------------------------------------------------------------------
// ws layout (bytes):
//   [0,    4N)        : na      (float) exact fp32 row norms, SORTED order
//   [4N,   8N)        : pos     (uint)  hard-positive d bits, sorted order
//   [8N,  12N)        : neg     (uint)  hard-negative d bits, sorted order
//   [12N, 16N)        : sid     (int)   sorted ids
//   [16N, 16N+2048)   : bincur  (int)   bin write cursors (hist+scan output)
//   [16N+2048, +128)  : partial (float[32])
//   [16N+4096, +2MB)  : H       (fp16)  [N][128], sorted order
// ---------------------------------------------------------------------------

// Single-block: histogram of ids into 512 bins + exclusive scan -> bin cursors.
__global__ __launch_bounds__(512) void hist_kernel(const int* __restrict__ ids,
                                                   int* __restrict__ bincur) {
    __shared__ int h[NUM_IDS];
    __shared__ int sc[NUM_IDS];
    const int tid = threadIdx.x;
    h[tid] = 0;
    __syncthreads();
#pragma unroll
    for (int i = 0; i < N / NUM_IDS; ++i) atomicAdd(&h[ids[i * NUM_IDS + tid]], 1);
    __syncthreads();
    int v = h[tid];
    sc[tid] = v;
    __syncthreads();
    for (int off = 1; off < NUM_IDS; off <<= 1) {
        int add = (tid >= off) ? sc[tid - off] : 0;
        __syncthreads();
        sc[tid] += add;
        __syncthreads();
    }
    bincur[tid] = sc[tid] - v;  // exclusive prefix = bin start
}

// Fused: counting-sort scatter + fp32->fp16 convert + exact norms + init.
__global__ __launch_bounds__(256) void prep_kernel(const float* __restrict__ A,
                                                   const int* __restrict__ ids,
                                                   int* __restrict__ bincur,
                                                   ushort_t* __restrict__ H,
                                                   float* __restrict__ na,
                                                   uint_t* __restrict__ pos,
                                                   uint_t* __restrict__ neg,
                                                   int* __restrict__ sid) {
    int t = blockIdx.x * 256 + threadIdx.x;  // 0 .. N*32-1
    int row = t >> 5, kg = t & 31;
    int lane = threadIdx.x & 63;
    int id = ids[row];
    float4 v = *reinterpret_cast<const float4*>(A + row * F + kg * 4);
    float f[4] = {v.x, v.y, v.z, v.w};
    ushort4 h;
    {
        _Float16 h0 = (_Float16)f[0], h1 = (_Float16)f[1], h2 = (_Float16)f[2], h3 = (_Float16)f[3];
        __builtin_memcpy(&h.x, &h0, 2);
        __builtin_memcpy(&h.y, &h1, 2);
        __builtin_memcpy(&h.z, &h2, 2);
        __builtin_memcpy(&h.w, &h3, 2);
    }
    float s = fmaf(f[0], f[0], fmaf(f[1], f[1], fmaf(f[2], f[2], f[3] * f[3])));
#pragma unroll
    for (int m = 1; m <= 16; m <<= 1) s += __shfl_xor(s, m, 64);  // 32-lane row groups
    int np = 0;
    if ((lane & 31) == 0) np = atomicAdd(&bincur[id], 1);  // sorted position
    np = __shfl(np, lane & 32, 64);                        // broadcast within row group
    *reinterpret_cast<ushort4*>(H + (size_t)np * F + kg * 4) = h;
    if ((lane & 31) == 0) {
        na[np] = s;
        sid[np] = id;
        pos[np] = 0u;
        neg[np] = NEG_FILL_BITS;
    }
}

// One 128x128 upper-triangular tile per block (2080 blocks), fp16 MFMA K=128.
// Sorted ids => ~94% of tiles have no same-id pair: compare-free min-only path.
__global__ __launch_bounds__(256) void hard_mine_mfma(const ushort_t* __restrict__ H,
                                                      const int* __restrict__ sid,
                                                      const float* __restrict__ na,
                                                      uint_t* __restrict__ pos,
                                                      uint_t* __restrict__ neg) {
    __shared__ __align__(16) ushort_t AsU[128 * 64];  // 16 KB, slot ^= row&7 swizzle
    __shared__ __align__(16) ushort_t BsU[128 * 64];  // 16 KB
    __shared__ uint_t ls_rp[128], ls_rn[128], ls_cp[128], ls_cn[128];

    const int tid = threadIdx.x;
    const int w = tid >> 6, lane = tid & 63;
    const int wr = w >> 1, wc = w & 1;  // wave's 64x64 quadrant

    // triangular decode: tile t -> (bi <= bj)
    int t = blockIdx.x;
    int bj = (int)((sqrtf(8.0f * (float)t + 1.0f) - 1.0f) * 0.5f);
    while ((bj + 1) * (bj + 2) / 2 <= t) ++bj;
    while (bj * (bj + 1) / 2 > t) --bj;
    const int bi = t - bj * (bj + 1) / 2;
    const int rowbase = bi * 128;
    const int colbase = bj * 128;

    // Sorted => tiles share an id iff boundary ids match (or diagonal).
    const bool shared_ids = (bi == bj) || (sid[rowbase + 127] == sid[colbase]);

    float myna[4][4];
#pragma unroll
    for (int m = 0; m < 4; ++m) {
        float4 v4 = *reinterpret_cast<const float4*>(
            na + rowbase + wr * 64 + m * 16 + (lane >> 4) * 4);
        myna[m][0] = v4.x; myna[m][1] = v4.y; myna[m][2] = v4.z; myna[m][3] = v4.w;
    }
    float nb[4];
#pragma unroll
    for (int n = 0; n < 4; ++n) nb[n] = na[colbase + wc * 64 + n * 16 + (lane & 15)];

    int myid[4][4];
    int jd[4];
    if (shared_ids) {
#pragma unroll
        for (int m = 0; m < 4; ++m) {
            int4 v4 = *reinterpret_cast<const int4*>(
                sid + rowbase + wr * 64 + m * 16 + (lane >> 4) * 4);
            myid[m][0] = v4.x; myid[m][1] = v4.y; myid[m][2] = v4.z; myid[m][3] = v4.w;
        }
#pragma unroll
        for (int n = 0; n < 4; ++n) jd[n] = sid[colbase + wc * 64 + n * 16 + (lane & 15)];
    }

    if (tid < 128) {
        ls_rn[tid] = NEG_FILL_BITS;
        ls_cn[tid] = NEG_FILL_BITS;
        if (shared_ids) {
            ls_rp[tid] = 0u;
            ls_cp[tid] = 0u;
        }
    }

    f32x4 acc[4][4];
#pragma unroll
    for (int m = 0; m < 4; ++m)
#pragma unroll
        for (int n = 0; n < 4; ++n)
            acc[m][n] = (f32x4)0.0f;

#pragma unroll
    for (int s = 0; s < 2; ++s) {
        const int koff = s * 64;
        __syncthreads();  // prev compute / ls-init done before LDS overwrite
#pragma unroll
        for (int i = 0; i < 4; ++i) {
            int chunk = w * 4 + i;              // 0..15 (1 KB each)
            int row = chunk * 8 + (lane >> 3);  // 0..127
            int ss = (lane & 7) ^ (row & 7);    // inverse-swizzled source slot
            const ushort_t* ga = H + (size_t)(rowbase + row) * F + koff + ss * 8;
            const ushort_t* gb = H + (size_t)(colbase + row) * F + koff + ss * 8;
            __builtin_amdgcn_global_load_lds(
                (const __attribute__((address_space(1))) uint_t*)ga,
                (__attribute__((address_space(3))) uint_t*)(AsU + chunk * 512), 16, 0, 0);
            __builtin_amdgcn_global_load_lds(
                (const __attribute__((address_space(1))) uint_t*)gb,
                (__attribute__((address_space(3))) uint_t*)(BsU + chunk * 512), 16, 0, 0);
        }
        __syncthreads();  // vmcnt(0) drain at barrier

#pragma unroll
        for (int ks = 0; ks < 2; ++ks) {
            half8 af[4], bfr[4];
            const int sl = ks * 4 + (lane >> 4);  // logical 16B slot
#pragma unroll
            for (int m = 0; m < 4; ++m) {
                int r = wr * 64 + m * 16 + (lane & 15);
                int ph = sl ^ (r & 7);
                af[m] = *reinterpret_cast<const half8*>(AsU + r * 64 + ph * 8);
            }
#pragma unroll
            for (int n = 0; n < 4; ++n) {
                int c = wc * 64 + n * 16 + (lane & 15);
                int ph = sl ^ (c & 7);
                bfr[n] = *reinterpret_cast<const half8*>(BsU + c * 64 + ph * 8);
            }
#pragma unroll
            for (int m = 0; m < 4; ++m)
#pragma unroll
                for (int n = 0; n < 4; ++n)
                    acc[m][n] = __builtin_amdgcn_mfma_f32_16x16x32_f16(
                        af[m], bfr[n], acc[m][n], 0, 0, 0);
        }
    }

    if (!shared_ids) {
        // ---- fast path: no same-id pairs -> neg mining only, no compares ----
        // row-side: nm[m][q] = min_j (nb[j]/2 - S);  col-side: cn[n] = min_i (na[i]/2 - S)
        float nm[4][4], cn[4];
        float nb2[4], myna2[4][4];
#pragma unroll
        for (int n = 0; n < 4; ++n) {
            nb2[n] = 0.5f * nb[n];
            cn[n] = PINF;
        }
#pragma unroll
        for (int m = 0; m < 4; ++m)
#pragma unroll
            for (int q = 0; q < 4; ++q) {
                myna2[m][q] = 0.5f * myna[m][q];
                nm[m][q] = PINF;
            }
#pragma unroll
        for (int m = 0; m < 4; ++m)
#pragma unroll
            for (int q = 0; q < 4; ++q) {
                float v0 = nb2[0] - acc[m][0][q];
                float v1 = nb2[1] - acc[m][1][q];
                float v2 = nb2[2] - acc[m][2][q];
                float v3 = nb2[3] - acc[m][3][q];
                float x = nm[m][q];
                x = fminf(fminf(x, v0), v1);  // v_min3
                x = fminf(fminf(x, v2), v3);
                nm[m][q] = x;
            }
#pragma unroll
        for (int n = 0; n < 4; ++n) {
            float c = cn[n];
#pragma unroll
            for (int m = 0; m < 4; ++m) {
                float w0 = myna2[m][0] - acc[m][n][0];
                float w1 = myna2[m][1] - acc[m][n][1];
                float w2 = myna2[m][2] - acc[m][n][2];
                float w3 = myna2[m][3] - acc[m][n][3];
                c = fminf(fminf(c, w0), w1);
                c = fminf(fminf(c, w2), w3);
            }
            cn[n] = c;
        }
#pragma unroll
        for (int mk = 1; mk < 16; mk <<= 1)
#pragma unroll
            for (int m = 0; m < 4; ++m)
#pragma unroll
                for (int q = 0; q < 4; ++q)
                    nm[m][q] = fminf(nm[m][q], __shfl_xor(nm[m][q], mk, 64));
#pragma unroll
        for (int mk = 16; mk < 64; mk <<= 1)
#pragma unroll
            for (int n = 0; n < 4; ++n)
                cn[n] = fminf(cn[n], __shfl_xor(cn[n], mk, 64));

        __syncthreads();  // ls init + LDS reads complete
        if ((lane & 15) == 0) {
#pragma unroll
            for (int m = 0; m < 4; ++m)
#pragma unroll
                for (int q = 0; q < 4; ++q) {
                    int rl = wr * 64 + m * 16 + (lane >> 4) * 4 + q;
                    float hn = sqrtf(fmaxf(fmaf(2.0f, nm[m][q], myna[m][q]), 0.0f) + 1e-12f);
                    atomicMin(&ls_rn[rl], __float_as_uint(hn));
                }
        }
        if (lane < 16) {
#pragma unroll
            for (int n = 0; n < 4; ++n) {
                int cl = wc * 64 + n * 16 + lane;
                float hn = sqrtf(fmaxf(fmaf(2.0f, cn[n], nb[n]), 0.0f) + 1e-12f);
                atomicMin(&ls_cn[cl], __float_as_uint(hn));
            }
        }
        __syncthreads();
        if (tid < 128) {
            atomicMin(&neg[rowbase + tid], ls_rn[tid]);
            atomicMin(&neg[colbase + tid], ls_cn[tid]);
        }
    } else {
        // ---- general path: per-element id compares, pos+neg dual-side ----
        float pm[4][4], nm[4][4], cp[4], cn[4];
#pragma unroll
        for (int m = 0; m < 4; ++m)
#pragma unroll
            for (int q = 0; q < 4; ++q) {
                pm[m][q] = NINF;
                nm[m][q] = PINF;
            }
#pragma unroll
        for (int n = 0; n < 4; ++n) {
            cp[n] = NINF;
            cn[n] = PINF;
        }
#pragma unroll
        for (int n = 0; n < 4; ++n) {
            const float nbv = nb[n];
            const int jdv = jd[n];
#pragma unroll
            for (int m = 0; m < 4; ++m)
#pragma unroll
                for (int q = 0; q < 4; ++q) {
                    float a = acc[m][n][q];
                    float vr = fmaf(-2.0f, a, nbv);
                    float vc = fmaf(-2.0f, a, myna[m][q]);
                    bool same = (jdv == myid[m][q]);
                    pm[m][q] = fmaxf(pm[m][q], same ? vr : NINF);
                    nm[m][q] = fminf(nm[m][q], same ? PINF : vr);
                    cp[n] = fmaxf(cp[n], same ? vc : NINF);
                    cn[n] = fminf(cn[n], same ? PINF : vc);
                }
        }
#pragma unroll
        for (int mk = 1; mk < 16; mk <<= 1)
#pragma unroll
            for (int m = 0; m < 4; ++m)
#pragma unroll
                for (int q = 0; q < 4; ++q) {
                    pm[m][q] = fmaxf(pm[m][q], __shfl_xor(pm[m][q], mk, 64));
                    nm[m][q] = fminf(nm[m][q], __shfl_xor(nm[m][q], mk, 64));
                }
#pragma unroll
        for (int mk = 16; mk < 64; mk <<= 1)
#pragma unroll
            for (int n = 0; n < 4; ++n) {
                cp[n] = fmaxf(cp[n], __shfl_xor(cp[n], mk, 64));
                cn[n] = fminf(cn[n], __shfl_xor(cn[n], mk, 64));
            }

        __syncthreads();
        if ((lane & 15) == 0) {
#pragma unroll
            for (int m = 0; m < 4; ++m)
#pragma unroll
                for (int q = 0; q < 4; ++q) {
                    int rl = wr * 64 + m * 16 + (lane >> 4) * 4 + q;
                    float hp = sqrtf(fmaxf(myna[m][q] + pm[m][q], 0.0f) + 1e-12f);
                    float hn = sqrtf(fmaxf(myna[m][q] + nm[m][q], 0.0f) + 1e-12f);
                    atomicMax(&ls_rp[rl], __float_as_uint(hp));
                    atomicMin(&ls_rn[rl], __float_as_uint(hn));
                }
        }
        if (lane < 16) {
#pragma unroll
            for (int n = 0; n < 4; ++n) {
                int cl = wc * 64 + n * 16 + lane;
                float hp = sqrtf(fmaxf(nb[n] + cp[n], 0.0f) + 1e-12f);
                float hn = sqrtf(fmaxf(nb[n] + cn[n], 0.0f) + 1e-12f);
                atomicMax(&ls_cp[cl], __float_as_uint(hp));
                atomicMin(&ls_cn[cl], __float_as_uint(hn));
            }
        }
        __syncthreads();
        if (tid < 128) {
            atomicMax(&pos[rowbase + tid], ls_rp[tid]);
            atomicMin(&neg[rowbase + tid], ls_rn[tid]);
            atomicMax(&pos[colbase + tid], ls_cp[tid]);
            atomicMin(&neg[colbase + tid], ls_cn[tid]);
        }
    }
}

__global__ __launch_bounds__(256) void row_loss_kernel(const uint_t* __restrict__ pos,
                                                       const uint_t* __restrict__ neg,
                                                       float* __restrict__ partial) {
    int r = blockIdx.x * 256 + threadIdx.x;
    float hp = __uint_as_float(pos[r]);
    float hn = __uint_as_float(neg[r]);  // huge if no negatives -> clamps to 0
    float loss = fmaxf(MARGIN + hp - hn, 0.0f);
#pragma unroll
    for (int m = 32; m >= 1; m >>= 1) loss += __shfl_xor(loss, m, 64);
    __shared__ float wsum[4];
    int lane = threadIdx.x & 63;
    int wave = threadIdx.x >> 6;
    if (lane == 0) wsum[wave] = loss;
    __syncthreads();
    if (threadIdx.x == 0) partial[blockIdx.x] = wsum[0] + wsum[1] + wsum[2] + wsum[3];
}

__global__ __launch_bounds__(64) void final_kernel(const float* __restrict__ partial,
                                                   float* __restrict__ out) {
    float v = (threadIdx.x < 32) ? partial[threadIdx.x] : 0.0f;
#pragma unroll
    for (int m = 32; m >= 1; m >>= 1) v += __shfl_xor(v, m, 64);
    if (threadIdx.x == 0) out[0] = v * (1.0f / (float)N);  // LOSS_FACTOR == 1
}

extern "C" void kernel_launch(void* const* d_in, const int* in_sizes, int n_in,
                              void* d_out, int out_size, void* d_ws, size_t ws_size,
                              hipStream_t stream) {
    (void)in_sizes; (void)n_in; (void)out_size; (void)ws_size;
    const float* A = (const float*)d_in[0];
    const int* ids = (const int*)d_in[1];
    float* out = (float*)d_out;

    char* ws = (char*)d_ws;
    float* na = (float*)ws;
    uint_t* pos = (uint_t*)(ws + 4 * N);
    uint_t* neg = (uint_t*)(ws + 8 * N);
    int* sid = (int*)(ws + 12 * N);
    int* bincur = (int*)(ws + 16 * N);
    float* partial = (float*)(ws + 16 * N + 2048);
    ushort_t* H = (ushort_t*)(ws + 16 * N + 4096);

    hist_kernel<<<1, 512, 0, stream>>>(ids, bincur);
    prep_kernel<<<N * 32 / 256, 256, 0, stream>>>(A, ids, bincur, H, na, pos, neg, sid);
    hard_mine_mfma<<<64 * 65 / 2, 256, 0, stream>>>(H, sid, na, pos, neg);
    row_loss_kernel<<<N / 256, 256, 0, stream>>>(pos, neg, partial);
    final_kernel<<<1, 64, 0, stream>>>(partial, out);
}